// Round 1
// baseline (1726.169 us; speedup 1.0000x reference)
//
#include <hip/hip_runtime.h>
#include <cstdint>
#include <cstddef>

// Problem constants (match reference setup_inputs)
#define V_SIZE 50257
#define B_SIZE 8192
#define NUM_NEG 5
#define TOTAL_G (NUM_NEG * V_SIZE)          // 251285 gumbel draws
#define HALF_G  ((TOTAL_G + 1) / 2)         // 125643 (odd size -> zero pad)

// ---------------- JAX threefry2x32, key = PRNGKey(42) = (0, 42) --------------
__device__ __forceinline__ unsigned rotl32(unsigned x, unsigned r) {
  return (x << r) | (x >> (32u - r));
}

__device__ __forceinline__ void threefry2x32_42(unsigned x0, unsigned x1,
                                                unsigned& o0, unsigned& o1) {
  const unsigned k0 = 0u;
  const unsigned k1 = 42u;
  const unsigned k2 = 0x1BD11BDAu ^ 0u ^ 42u;
  x0 += k0; x1 += k1;
#define TF_ROUND(r) { x0 += x1; x1 = rotl32(x1, r); x1 ^= x0; }
  TF_ROUND(13u) TF_ROUND(15u) TF_ROUND(26u) TF_ROUND(6u)
  x0 += k1; x1 += k2 + 1u;
  TF_ROUND(17u) TF_ROUND(29u) TF_ROUND(16u) TF_ROUND(24u)
  x0 += k2; x1 += k0 + 2u;
  TF_ROUND(13u) TF_ROUND(15u) TF_ROUND(26u) TF_ROUND(6u)
  x0 += k0; x1 += k1 + 3u;
  TF_ROUND(17u) TF_ROUND(29u) TF_ROUND(16u) TF_ROUND(24u)
  x0 += k1; x1 += k2 + 4u;
  TF_ROUND(13u) TF_ROUND(15u) TF_ROUND(26u) TF_ROUND(6u)
  x0 += k2; x1 += k0 + 5u;
#undef TF_ROUND
  o0 = x0; o1 = x1;
}

// Gumbel noise at flat position p of the (5, V) array, exactly as JAX:
// bits = threefry_2x32([0,42], iota(u32, 251285)) with odd-size padding:
//   padded counts split: x0[i]=i, x1[i]= (i==HALF-1) ? 0 : i+HALF
//   out = concat(out0, out1)[:TOTAL]
// uniform: f = bitcast((bits>>9)|0x3F800000) - 1;  u = max(tiny, f*(1-tiny)+tiny)
//   note (1-tiny) rounds to 1.0f in fp32, so u = max(tiny, f + tiny)
// gumbel: -log(-log(u))
__device__ __forceinline__ float gumbel_at(unsigned p) {
  unsigned i  = (p < HALF_G) ? p : (p - HALF_G);
  unsigned x0 = i;
  unsigned x1 = (i == HALF_G - 1u) ? 0u : (i + HALF_G);
  unsigned o0, o1;
  threefry2x32_42(x0, x1, o0, o1);
  unsigned bits = (p < HALF_G) ? o0 : o1;
  float f = __uint_as_float((bits >> 9) | 0x3F800000u) - 1.0f;
  const float tiny = 1.17549435e-38f;  // finfo(f32).tiny
  float u = fmaxf(tiny, f + tiny);
  return -logf(-logf(u));
}

// ---------------- workspace layout ----------------
// [0,8)    double num
// [8,16)   double den
// [16,56)  u64 neg_enc[5]
// [56,60)  float norm_sq
// [64, 64+4V)        int cnt[V]
// [64+4V, 64+8V)     float logits[V]
#define ZERO_WORDS (16 + V_SIZE)   // zero bytes [0, 64+4V) as u32 words

// K0: zero the stateful part of ws (harness poisons ws with 0xAA每 call)
__global__ void k0_zero(unsigned* __restrict__ w) {
  int idx = blockIdx.x * blockDim.x + threadIdx.x;
  for (int j = idx; j < ZERO_WORDS; j += gridDim.x * blockDim.x) w[j] = 0u;
}

// K1: cnt[target[i]]++ (i<B) and norm_sq = sum((wf^0.75)^2) (v<V)
__global__ void k1_count_sumsq(const int* __restrict__ target,
                               const float* __restrict__ wf,
                               int* __restrict__ cnt,
                               float* __restrict__ norm_sq) {
  int v = blockIdx.x * blockDim.x + threadIdx.x;
  float part = 0.0f;
  if (v < V_SIZE) { float d = powf(wf[v], 0.75f); part = d * d; }
  if (v < B_SIZE) { atomicAdd(&cnt[target[v]], 1); }
#pragma unroll
  for (int off = 32; off > 0; off >>= 1) part += __shfl_down(part, off);
  __shared__ float sh[4];
  int lane = threadIdx.x & 63, wv = threadIdx.x >> 6;
  if (lane == 0) sh[wv] = part;
  __syncthreads();
  if (threadIdx.x == 0) atomicAdd(norm_sq, sh[0] + sh[1] + sh[2] + sh[3]);
}

// K2: logits[v] = log( pos ? 0 : (wf^0.75)/norm )   (log(0) = -inf masks positives)
__global__ void k2_logits(const float* __restrict__ wf,
                          const int* __restrict__ cnt,
                          const float* __restrict__ norm_sq,
                          float* __restrict__ logits) {
  int v = blockIdx.x * blockDim.x + threadIdx.x;
  if (v < V_SIZE) {
    float norm = sqrtf(*norm_sq);
    float d = powf(wf[v], 0.75f);
    float val = (cnt[v] > 0) ? 0.0f : (d / norm);
    logits[v] = logf(val);
  }
}

// K3: per sample s, argmax_v (gumbel[s,v] + logits[v]); first-index tie-break.
// Encode (score, ~v) into u64 so atomicMax is order-correct across blocks.
#define BLOCKS_PER_S 32
__global__ void k3_sample(const float* __restrict__ logits,
                          unsigned long long* __restrict__ neg_enc) {
  int s     = blockIdx.x / BLOCKS_PER_S;
  int chunk = blockIdx.x % BLOCKS_PER_S;
  float best = -__builtin_inff();
  unsigned bestv = 0xFFFFFFFFu;
  for (unsigned v = chunk * 256u + threadIdx.x; v < V_SIZE;
       v += BLOCKS_PER_S * 256u) {
    float lg = logits[v];
    if (lg == -__builtin_inff()) continue;  // masked positive / zero-freq: can't win
    float sc = gumbel_at((unsigned)s * V_SIZE + v) + lg;
    if (sc > best) { best = sc; bestv = v; }  // increasing scan: keeps smallest v on ties
  }
#pragma unroll
  for (int off = 32; off > 0; off >>= 1) {
    float os = __shfl_down(best, off);
    unsigned ov = __shfl_down(bestv, off);
    if (os > best || (os == best && ov < bestv)) { best = os; bestv = ov; }
  }
  __shared__ float sh_s[4];
  __shared__ unsigned sh_v[4];
  int lane = threadIdx.x & 63, wv = threadIdx.x >> 6;
  if (lane == 0) { sh_s[wv] = best; sh_v[wv] = bestv; }
  __syncthreads();
  if (threadIdx.x == 0) {
#pragma unroll
    for (int w = 1; w < 4; w++) {
      if (sh_s[w] > best || (sh_s[w] == best && sh_v[w] < bestv)) {
        best = sh_s[w]; bestv = sh_v[w];
      }
    }
    if (bestv != 0xFFFFFFFFu) {
      unsigned fb  = __float_as_uint(best);
      unsigned enc = (fb & 0x80000000u) ? ~fb : (fb | 0x80000000u);
      unsigned long long key =
          ((unsigned long long)enc << 32) | (unsigned)(~bestv);
      atomicMax(&neg_enc[s], key);
    }
  }
}

// K4: decode negatives, bump their counts
__global__ void k4_add_neg(const unsigned long long* __restrict__ neg_enc,
                           int* __restrict__ cnt) {
  int s = threadIdx.x;
  if (s < NUM_NEG) {
    unsigned v = ~(unsigned)(neg_enc[s] & 0xFFFFFFFFull);
    atomicAdd(&cnt[v], 1);
  }
}

// K5: num = sum_i w[t_i] * input[i, t_i]; den = sum_i w[t_i]
__global__ void k5_gather(const float* __restrict__ input,
                          const int* __restrict__ target,
                          const int* __restrict__ cnt,
                          double* __restrict__ num, double* __restrict__ den) {
  int i = blockIdx.x * blockDim.x + threadIdx.x;
  double n = 0.0, d = 0.0;
  if (i < B_SIZE) {
    int t = target[i];
    double w = (double)cnt[t];
    double x = (double)input[(size_t)i * V_SIZE + t];
    n = w * x;
    d = w;
  }
#pragma unroll
  for (int off = 32; off > 0; off >>= 1) {
    n += __shfl_down(n, off);
    d += __shfl_down(d, off);
  }
  __shared__ double sn[4], sd[4];
  int lane = threadIdx.x & 63, wv = threadIdx.x >> 6;
  if (lane == 0) { sn[wv] = n; sd[wv] = d; }
  __syncthreads();
  if (threadIdx.x == 0) {
    atomicAdd(num, sn[0] + sn[1] + sn[2] + sn[3]);
    atomicAdd(den, sd[0] + sd[1] + sd[2] + sd[3]);
  }
}

// K6: out = -num/den
__global__ void k6_final(const double* __restrict__ num,
                         const double* __restrict__ den,
                         float* __restrict__ out) {
  if (threadIdx.x == 0 && blockIdx.x == 0) out[0] = (float)(-(*num) / (*den));
}

extern "C" void kernel_launch(void* const* d_in, const int* in_sizes, int n_in,
                              void* d_out, int out_size, void* d_ws, size_t ws_size,
                              hipStream_t stream) {
  const float* input  = (const float*)d_in[0];   // [B, V] f32
  const int*   target = (const int*)d_in[1];     // [B] int
  const float* wf     = (const float*)d_in[2];   // [V] f32
  float* out = (float*)d_out;

  uint8_t* w = (uint8_t*)d_ws;
  double* num = (double*)(w + 0);
  double* den = (double*)(w + 8);
  unsigned long long* neg_enc = (unsigned long long*)(w + 16);
  float* norm_sq = (float*)(w + 56);
  int*   cnt     = (int*)(w + 64);
  float* logits  = (float*)(w + 64 + 4 * (size_t)V_SIZE);

  const int T = 256;
  const int vblocks = (V_SIZE + T - 1) / T;  // 197

  k0_zero<<<64, T, 0, stream>>>((unsigned*)d_ws);
  k1_count_sumsq<<<vblocks, T, 0, stream>>>(target, wf, cnt, norm_sq);
  k2_logits<<<vblocks, T, 0, stream>>>(wf, cnt, norm_sq, logits);
  k3_sample<<<NUM_NEG * BLOCKS_PER_S, T, 0, stream>>>(logits, neg_enc);
  k4_add_neg<<<1, 64, 0, stream>>>(neg_enc, cnt);
  k5_gather<<<(B_SIZE + T - 1) / T, T, 0, stream>>>(input, target, cnt, num, den);
  k6_final<<<1, 64, 0, stream>>>(num, den, out);
}